// Round 9
// baseline (42.216 us; speedup 1.0000x reference)
//
#include <hip/hip_runtime.h>

// Problem dims (fixed by reference)
constexpr int T = 64, B = 8, A = 3, S = 400, V = 50000, N_OOV = 400;
constexpr int V_EXT  = V + N_OOV;      // 50400
constexpr int NSUB   = 8;              // slices per (t,b): 25.2 KB LDS -> 6 blocks/CU
constexpr int C_SUB  = V_EXT / NSUB;   // 6300 floats per slice
constexpr int C4_SUB = C_SUB / 4;      // 1575 float4 per slice
constexpr int V4     = V / 4;          // 12500 float4 of base vocab
constexpr int NTHR   = 256;
constexpr int FULL_K = C4_SUB / NTHR;  // 6 full strides (+39-thread tail)
constexpr int NSC    = 5;              // ceil(A*S / NTHR) scatter entries/thread
constexpr int NWG    = T * B * NSUB;   // 4096
constexpr int NXCD   = 8;
constexpr int WG_PER_XCD = NWG / NXCD; // 512

// One block per (t,b,slice).
//   entry loads -> zero LDS -> barrier -> LDS scatter -> barrier ->
//   combine: SIX batched float4 loads (same BB as stores -- survives
//   codegen, R4 evidence VGPR=40) + coalesced stores.
// XCD-aware bijective swizzle: each XCD owns a contiguous 1/8 of the
// logical id space (contiguous out region + shared article/aw lines).
__global__ __launch_bounds__(NTHR, 6) void pg_mlp_kernel(
    const int*   __restrict__ article,        // [S,B,A]
    const float* __restrict__ vocab_probs,    // [T,B,V]
    const float* __restrict__ gen_probs,      // [T,B,A]
    const float* __restrict__ agentwise_attn, // [T,B,A,S]
    const float* __restrict__ agent_attn,     // [T,B,A]
    float*       __restrict__ out)            // [T,B,V_EXT]
{
    __shared__ float acc[C_SUB];               // 25200 B
    // bijective XCD swizzle (nwg = 4096 = 8 * 512)
    const int bid = (blockIdx.x & (NXCD - 1)) * WG_PER_XCD + (blockIdx.x >> 3);
    const int tb  = bid / NSUB;                // t*B + b
    const int sub = bid - tb * NSUB;
    const int b   = tb % B;
    const int tid = threadIdx.x;

    // per-(t,b) scalars
    float coef = 0.f;
    float cw[A];
#pragma unroll
    for (int a = 0; a < A; ++a) {
        const float aa = agent_attn[tb * A + a];
        const float g  = gen_probs[tb * A + a];
        coef += aa * g;
        cw[a] = aa * (1.f - g);
    }

    // scatter-entry loads (overlap the LDS-zero phase)
    int   sidx[NSC];
    float sraw[NSC];
    const float* aw = agentwise_attn + (size_t)tb * A * S;   // flat [a*S+s]
#pragma unroll
    for (int j = 0; j < NSC; ++j) {
        const int i2 = tid + j * NTHR;
        sidx[j] = -1; sraw[j] = 0.f;
        if (i2 < A * S) {
            const int a = (i2 >= 2 * S) ? 2 : (i2 >= S ? 1 : 0);
            const int s = i2 - a * S;
            sidx[j] = article[(s * B + b) * A + a];
            sraw[j] = aw[i2];
        }
    }

    // zero the slice accumulator
    float4* acc4 = reinterpret_cast<float4*>(acc);
    for (int j = tid; j < C4_SUB; j += NTHR)
        acc4[j] = make_float4(0.f, 0.f, 0.f, 0.f);
    __syncthreads();

    // scatter from registers into LDS (filtered to this slice)
    const int lo = sub * C_SUB;
    const int hi = lo + C_SUB;
#pragma unroll
    for (int j = 0; j < NSC; ++j) {
        if (sidx[j] >= lo && sidx[j] < hi) {
            const int i2 = tid + j * NTHR;
            const int a  = (i2 >= 2 * S) ? 2 : (i2 >= S ? 1 : 0);
            atomicAdd(&acc[sidx[j] - lo], cw[a] * sraw[j]);
        }
    }
    __syncthreads();

    // combine: 6 batched loads + tail, then stores (one basic block)
    const float4* vp4  = reinterpret_cast<const float4*>(vocab_probs + (size_t)tb * V);
    float4*       out4 = reinterpret_cast<float4*>(out + (size_t)tb * V_EXT);
    const int base = sub * C4_SUB;
    const int i0   = base + tid;

    float4 v[FULL_K];
#pragma unroll
    for (int k = 0; k < FULL_K; ++k) {
        const int i  = i0 + k * NTHR;
        const int ic = (i < V4) ? i : (V4 - 1);   // clamp (only slice 7 mixes)
        v[k] = vp4[ic];
    }
    const int  it       = i0 + FULL_K * NTHR;
    const bool has_tail = (it < base + C4_SUB);   // 39 threads per block
    float4 vt = make_float4(0.f, 0.f, 0.f, 0.f);
    if (has_tail) vt = vp4[(it < V4) ? it : (V4 - 1)];

#pragma unroll
    for (int k = 0; k < FULL_K; ++k) {
        const int i = i0 + k * NTHR;
        float4 r = acc4[i - base];
        if (i < V4) {
            r.x += coef * v[k].x;  r.y += coef * v[k].y;
            r.z += coef * v[k].z;  r.w += coef * v[k].w;
        }
        out4[i] = r;
    }
    if (has_tail) {
        float4 r = acc4[it - base];
        if (it < V4) {
            r.x += coef * vt.x;  r.y += coef * vt.y;
            r.z += coef * vt.z;  r.w += coef * vt.w;
        }
        out4[it] = r;
    }
}

extern "C" void kernel_launch(void* const* d_in, const int* in_sizes, int n_in,
                              void* d_out, int out_size, void* d_ws, size_t ws_size,
                              hipStream_t stream) {
    const int*   article        = (const int*)  d_in[0]; // [S,B,A]
    const float* vocab_probs    = (const float*)d_in[1]; // [T,B,V]
    const float* gen_probs      = (const float*)d_in[2]; // [T,B,A]
    const float* agentwise_attn = (const float*)d_in[3]; // [T,B,A,S]
    const float* agent_attn     = (const float*)d_in[4]; // [T,B,A]
    float*       out            = (float*)d_out;         // [T,B,V_EXT]

    pg_mlp_kernel<<<dim3(NWG), dim3(NTHR), 0, stream>>>(
        article, vocab_probs, gen_probs, agentwise_attn, agent_attn, out);
}

// Round 10
// 38.690 us; speedup vs baseline: 1.0911x; 1.0911x over previous
//
#include <hip/hip_runtime.h>

// Problem dims (fixed by reference)
constexpr int T = 64, B = 8, A = 3, S = 400, V = 50000, N_OOV = 400;
constexpr int V_EXT  = V + N_OOV;      // 50400
constexpr int NSUB   = 6;              // slices per (t,b): 33600 B each (64B-aligned!)
constexpr int C_SUB  = V_EXT / NSUB;   // 8400 floats per slice
constexpr int C4_SUB = C_SUB / 4;      // 2100 float4 per slice
constexpr int V4     = V / 4;          // 12500 float4 of base vocab
constexpr int NTHR   = 512;
constexpr int FULL_K = C4_SUB / NTHR;  // 4 full strides (+52-thread tail)
constexpr int NSC    = 3;              // ceil(A*S / NTHR)
constexpr int NBLK   = T * B * NSUB / 3; // 1024 = exactly 4 blocks/CU, one round

// Persistent block: handles the 3 slices of one (tb, half).
//  - entries (1200 idx+weight) and coef/cw loaded ONCE, reused for 3 scatters
//  - per unit: combine (heavy mem burst, 4-deep batched loads) then
//    {raw-barrier, zero LDS, raw-barrier, scatter, raw-barrier} — all tiny,
//    no vmcnt drains anywhere (barriers order LDS only; each wave consumes
//    only its own global loads).
__global__ __launch_bounds__(NTHR, 8) void pg_persist_kernel(
    const int*   __restrict__ article,        // [S,B,A]
    const float* __restrict__ vocab_probs,    // [T,B,V]
    const float* __restrict__ gen_probs,      // [T,B,A]
    const float* __restrict__ agentwise_attn, // [T,B,A,S]
    const float* __restrict__ agent_attn,     // [T,B,A]
    float*       __restrict__ out)            // [T,B,V_EXT]
{
    __shared__ float acc[C_SUB];               // 33600 B
    const int blk  = blockIdx.x;
    const int tb   = blk >> 1;                 // t*B + b
    const int half = blk & 1;                  // slices {0,1,2} or {3,4,5}
    const int b    = tb % B;
    const int tid  = threadIdx.x;

    // per-(t,b) scalars (once per block)
    float coef = 0.f;
    float cw[A];
#pragma unroll
    for (int a = 0; a < A; ++a) {
        const float aa = agent_attn[tb * A + a];
        const float g  = gen_probs[tb * A + a];
        coef += aa * g;
        cw[a] = aa * (1.f - g);
    }

    // scatter entries: loaded ONCE, reused for all 3 units
    int   sidx[NSC];
    float sw[NSC];
    const float* aw = agentwise_attn + (size_t)tb * A * S;   // flat [a*S+s]
#pragma unroll
    for (int j = 0; j < NSC; ++j) {
        const int i2 = tid + j * NTHR;
        sidx[j] = -1; sw[j] = 0.f;
        if (i2 < A * S) {
            const int a = (i2 >= 2 * S) ? 2 : (i2 >= S ? 1 : 0);
            const int s = i2 - a * S;
            sidx[j] = article[(s * B + b) * A + a];
            sw[j]   = cw[a] * aw[i2];
        }
    }

    float4* acc4 = reinterpret_cast<float4*>(acc);
    const float4* vp4  = reinterpret_cast<const float4*>(vocab_probs + (size_t)tb * V);
    float4*       out4 = reinterpret_cast<float4*>(out + (size_t)tb * V_EXT);

    // prologue: zero + scatter for unit 0
    for (int j = tid; j < C4_SUB; j += NTHR)
        acc4[j] = make_float4(0.f, 0.f, 0.f, 0.f);
    asm volatile("s_waitcnt lgkmcnt(0)" ::: "memory");
    __builtin_amdgcn_s_barrier();
    __builtin_amdgcn_sched_barrier(0);
    {
        const int lo = (half * 3) * C_SUB;
#pragma unroll
        for (int j = 0; j < NSC; ++j)
            if (sidx[j] >= lo && sidx[j] < lo + C_SUB)
                atomicAdd(&acc[sidx[j] - lo], sw[j]);
    }
    asm volatile("s_waitcnt lgkmcnt(0)" ::: "memory");
    __builtin_amdgcn_s_barrier();
    __builtin_amdgcn_sched_barrier(0);

    for (int u = 0; u < 3; ++u) {
        const int sub  = half * 3 + u;
        const int base = sub * C4_SUB;
        const int i0   = base + tid;

        // combine: 4 batched loads (+tail) then fma+store, one basic block
        float4 v[FULL_K];
#pragma unroll
        for (int k = 0; k < FULL_K; ++k) {
            const int i  = i0 + k * NTHR;
            const int ic = (i < V4) ? i : (V4 - 1);   // only slice 5 mixes
            v[k] = vp4[ic];
        }
        const int  it       = i0 + FULL_K * NTHR;
        const bool has_tail = (it < base + C4_SUB);   // 52 threads
        float4 vt = make_float4(0.f, 0.f, 0.f, 0.f);
        if (has_tail) vt = vp4[(it < V4) ? it : (V4 - 1)];

#pragma unroll
        for (int k = 0; k < FULL_K; ++k) {
            const int i = i0 + k * NTHR;
            float4 r = acc4[i - base];
            if (i < V4) {
                r.x += coef * v[k].x;  r.y += coef * v[k].y;
                r.z += coef * v[k].z;  r.w += coef * v[k].w;
            }
            out4[i] = r;
        }
        if (has_tail) {
            float4 r = acc4[it - base];
            if (it < V4) {
                r.x += coef * vt.x;  r.y += coef * vt.y;
                r.z += coef * vt.z;  r.w += coef * vt.w;
            }
            out4[it] = r;
        }

        if (u < 2) {
            // acc reads done (own ds_reads: lgkmcnt; others signal via barrier)
            asm volatile("s_waitcnt lgkmcnt(0)" ::: "memory");
            __builtin_amdgcn_s_barrier();
            __builtin_amdgcn_sched_barrier(0);
            // re-zero
            for (int j = tid; j < C4_SUB; j += NTHR)
                acc4[j] = make_float4(0.f, 0.f, 0.f, 0.f);
            asm volatile("s_waitcnt lgkmcnt(0)" ::: "memory");
            __builtin_amdgcn_s_barrier();
            __builtin_amdgcn_sched_barrier(0);
            // scatter next unit from registers (no reloads)
            const int lo = (sub + 1) * C_SUB;
#pragma unroll
            for (int j = 0; j < NSC; ++j)
                if (sidx[j] >= lo && sidx[j] < lo + C_SUB)
                    atomicAdd(&acc[sidx[j] - lo], sw[j]);
            asm volatile("s_waitcnt lgkmcnt(0)" ::: "memory");
            __builtin_amdgcn_s_barrier();
            __builtin_amdgcn_sched_barrier(0);
        }
    }
}

extern "C" void kernel_launch(void* const* d_in, const int* in_sizes, int n_in,
                              void* d_out, int out_size, void* d_ws, size_t ws_size,
                              hipStream_t stream) {
    const int*   article        = (const int*)  d_in[0]; // [S,B,A]
    const float* vocab_probs    = (const float*)d_in[1]; // [T,B,V]
    const float* gen_probs      = (const float*)d_in[2]; // [T,B,A]
    const float* agentwise_attn = (const float*)d_in[3]; // [T,B,A,S]
    const float* agent_attn     = (const float*)d_in[4]; // [T,B,A]
    float*       out            = (float*)d_out;         // [T,B,V_EXT]

    pg_persist_kernel<<<dim3(NBLK), dim3(NTHR), 0, stream>>>(
        article, vocab_probs, gen_probs, agentwise_attn, agent_attn, out);
}